// Round 1
// baseline (1152.679 us; speedup 1.0000x reference)
//
#include <hip/hip_runtime.h>
#include <hip/hip_bf16.h>

// Problem constants (match reference)
#define NUM_MIRNA 20000
#define NUM_GENE  30000
#define NN        50000      // total nodes
#define RR        4          // relations
#define EE        1000000    // edges
#define IN_C      128
#define HIDC      128
#define OUTC      64
#define NBASIS    10

// ---------------------------------------------------------------------------
// W[r] = sum_b comp[r,b] * basis[b]   (basis: [NB, IO] flattened per r slice)
// grid: (ceil(IO/256), R)
__global__ void wcomb_k(const float* __restrict__ comp,
                        const float* __restrict__ basis,
                        float* __restrict__ W, int IO) {
    int r = blockIdx.y;
    int idx = blockIdx.x * 256 + threadIdx.x;
    if (idx >= IO) return;
    float acc = 0.f;
#pragma unroll
    for (int b = 0; b < NBASIS; ++b)
        acc += comp[r * NBASIS + b] * basis[(size_t)b * IO + idx];
    W[(size_t)r * IO + idx] = acc;
}

// ---------------------------------------------------------------------------
// Generic fp32 GEMM: C[M,OC] = A[M,K] @ W[K,OC] (+bias) (+addsrc)
// blockIdx.z selects relation slice: W += z*K*OC, C += z*M*OC
// Block = 256 threads, TM=32 rows per block, K consumed in chunks of 128.
template <int OC>
__global__ void gemm_k(const float* __restrict__ A,
                       const float* __restrict__ W,
                       const float* __restrict__ bias,
                       const float* __restrict__ addsrc,
                       float* __restrict__ C, int M, int K) {
    constexpr int TM  = 32;
    constexpr int NG  = 256 / OC;   // thread row-groups per block
    constexpr int RPT = TM / NG;    // rows per thread

    const int z = blockIdx.z;
    const float* Wp = W + (size_t)z * K * OC;
    float* Cp = C + (size_t)z * (size_t)M * OC;

    const int tid  = threadIdx.x;
    const int o    = tid % OC;
    const int tg   = tid / OC;
    const int rbase = tg * RPT;
    const int row0 = blockIdx.x * TM;

    float acc[RPT];
#pragma unroll
    for (int i = 0; i < RPT; ++i) acc[i] = 0.f;

    __shared__ float4 As[TM][32];   // 32 rows x 128 k-floats = 16 KB

    for (int kc = 0; kc < K; kc += 128) {
        // cooperative load of A tile: 1024 float4 by 256 threads
#pragma unroll
        for (int i = 0; i < 4; ++i) {
            int idx = tid + i * 256;      // 0..1023
            int rr = idx >> 5;            // row in tile
            int cc = idx & 31;            // float4 column
            int grow = row0 + rr;
            float4 v = make_float4(0.f, 0.f, 0.f, 0.f);
            if (grow < M)
                v = *(const float4*)(A + (size_t)grow * K + kc + cc * 4);
            As[rr][cc] = v;
        }
        __syncthreads();

        for (int k4 = 0; k4 < 32; ++k4) {
            int k = kc + k4 * 4;
            float w0 = Wp[(size_t)(k + 0) * OC + o];
            float w1 = Wp[(size_t)(k + 1) * OC + o];
            float w2 = Wp[(size_t)(k + 2) * OC + o];
            float w3 = Wp[(size_t)(k + 3) * OC + o];
#pragma unroll
            for (int i = 0; i < RPT; ++i) {
                float4 a = As[rbase + i][k4];
                acc[i] = fmaf(a.x, w0,
                         fmaf(a.y, w1,
                         fmaf(a.z, w2,
                         fmaf(a.w, w3, acc[i]))));
            }
        }
        __syncthreads();
    }

#pragma unroll
    for (int i = 0; i < RPT; ++i) {
        int grow = row0 + rbase + i;
        if (grow < M) {
            float v = acc[i];
            if (bias)   v += bias[o];
            if (addsrc) v += addsrc[(size_t)grow * OC + o];
            Cp[(size_t)grow * OC + o] = v;
        }
    }
}

// ---------------------------------------------------------------------------
// per-(relation,dst) edge counts
__global__ void count_k(const int* __restrict__ et, const int* __restrict__ dstA,
                        float* __restrict__ cnt, int E) {
    int e = blockIdx.x * 256 + threadIdx.x;
    if (e < E) atomicAdd(&cnt[et[e] * NN + dstA[e]], 1.0f);
}

__global__ void inv_k(const float* __restrict__ cnt, float* __restrict__ inv, int n) {
    int i = blockIdx.x * 256 + threadIdx.x;
    if (i < n) inv[i] = 1.0f / fmaxf(cnt[i], 1.0f);
}

// ---------------------------------------------------------------------------
// scatter: out[dst] += h[etype, src] * inv[etype*N+dst]
// OC threads per edge (one column each).
template <int OC>
__global__ void scatter_k(const float* __restrict__ h,
                          const int* __restrict__ srcA,
                          const int* __restrict__ dstA,
                          const int* __restrict__ et,
                          const float* __restrict__ inv,
                          float* __restrict__ out, int E) {
    constexpr int EPB = 256 / OC;
    int e = blockIdx.x * EPB + threadIdx.x / OC;
    int c = threadIdx.x % OC;
    if (e >= E) return;
    int r = et[e];
    int s = srcA[e];
    int d = dstA[e];
    float w = inv[r * NN + d];
    float v = h[((size_t)r * NN + s) * OC + c] * w;
    atomicAdd(&out[(size_t)d * OC + c], v);
}

// ---------------------------------------------------------------------------
extern "C" void kernel_launch(void* const* d_in, const int* in_sizes, int n_in,
                              void* d_out, int out_size, void* d_ws, size_t ws_size,
                              hipStream_t stream) {
    const float* x_mirna = (const float*)d_in[0];
    const float* x_gene  = (const float*)d_in[1];
    const int*   eidx    = (const int*)d_in[2];
    const int*   etype   = (const int*)d_in[3];
    const float* lin_w_m = (const float*)d_in[4];
    const float* lin_b_m = (const float*)d_in[5];
    const float* lin_w_g = (const float*)d_in[6];
    const float* lin_b_g = (const float*)d_in[7];
    const float* comp1   = (const float*)d_in[8];
    const float* basis1  = (const float*)d_in[9];
    const float* root1   = (const float*)d_in[10];
    const float* bias1   = (const float*)d_in[11];
    const float* comp2   = (const float*)d_in[12];
    const float* basis2  = (const float*)d_in[13];
    const float* root2   = (const float*)d_in[14];
    const float* bias2   = (const float*)d_in[15];

    const int* srcA = eidx;        // edge_index[0]
    const int* dstA = eidx + EE;   // edge_index[1]

    // workspace layout (floats)
    float* ws = (float*)d_ws;
    size_t off = 0;
    float* W1  = ws + off; off += (size_t)RR * IN_C * HIDC;   // 65536
    float* W2  = ws + off; off += (size_t)RR * HIDC * OUTC;   // 32768
    float* x0  = ws + off; off += (size_t)NN * IN_C;          // 6.4M
    float* h1  = ws + off; off += (size_t)RR * NN * HIDC;     // 25.6M
    float* h2  = ws + off; off += (size_t)RR * NN * OUTC;     // 12.8M
    float* x1  = ws + off; off += (size_t)NN * HIDC;          // 6.4M
    float* cnt = ws + off; off += (size_t)RR * NN;            // 200k
    float* inv = ws + off; off += (size_t)RR * NN;            // 200k

    float* outp = (float*)d_out;   // [NN, OUTC] fp32

    // zero the accumulators
    hipMemsetAsync(cnt, 0, (size_t)RR * NN * sizeof(float), stream);
    hipMemsetAsync(x1,  0, (size_t)NN * HIDC * sizeof(float), stream);
    hipMemsetAsync(d_out, 0, (size_t)NN * OUTC * sizeof(float), stream);

    // relation weights from basis decomposition
    wcomb_k<<<dim3((IN_C * HIDC + 255) / 256, RR), 256, 0, stream>>>(comp1, basis1, W1, IN_C * HIDC);
    wcomb_k<<<dim3((HIDC * OUTC + 255) / 256, RR), 256, 0, stream>>>(comp2, basis2, W2, HIDC * OUTC);

    // input projections -> x0
    gemm_k<IN_C><<<dim3((NUM_MIRNA + 31) / 32, 1, 1), 256, 0, stream>>>(
        x_mirna, lin_w_m, lin_b_m, nullptr, x0, NUM_MIRNA, 256);
    gemm_k<IN_C><<<dim3((NUM_GENE + 31) / 32, 1, 1), 256, 0, stream>>>(
        x_gene, lin_w_g, lin_b_g, nullptr, x0 + (size_t)NUM_MIRNA * IN_C, NUM_GENE, 512);

    // per-(relation,dst) inverse counts (shared by both layers)
    count_k<<<(EE + 255) / 256, 256, 0, stream>>>(etype, dstA, cnt, EE);
    inv_k<<<(RR * NN + 255) / 256, 256, 0, stream>>>(cnt, inv, RR * NN);

    // layer 1: h1[r] = x0 @ W1[r]
    gemm_k<HIDC><<<dim3((NN + 31) / 32, 1, RR), 256, 0, stream>>>(
        x0, W1, nullptr, nullptr, h1, NN, IN_C);
    // scatter mean-aggregation into x1
    scatter_k<HIDC><<<EE / (256 / HIDC), 256, 0, stream>>>(h1, srcA, dstA, etype, inv, x1, EE);
    // x1 += x0 @ root1 + bias1   (in-place add)
    gemm_k<HIDC><<<dim3((NN + 31) / 32, 1, 1), 256, 0, stream>>>(
        x0, root1, bias1, x1, x1, NN, IN_C);

    // layer 2: h2[r] = x1 @ W2[r]
    gemm_k<OUTC><<<dim3((NN + 31) / 32, 1, RR), 256, 0, stream>>>(
        x1, W2, nullptr, nullptr, h2, NN, HIDC);
    // scatter mean-aggregation into out
    scatter_k<OUTC><<<EE / (256 / OUTC), 256, 0, stream>>>(h2, srcA, dstA, etype, inv, outp, EE);
    // out += x1 @ root2 + bias2  (in-place add)
    gemm_k<OUTC><<<dim3((NN + 31) / 32, 1, 1), 256, 0, stream>>>(
        x1, root2, bias2, outp, outp, NN, HIDC);
}

// Round 2
// 767.084 us; speedup vs baseline: 1.5027x; 1.5027x over previous
//
#include <hip/hip_runtime.h>
#include <hip/hip_bf16.h>

// Problem constants (match reference)
#define NUM_MIRNA 20000
#define NUM_GENE  30000
#define NN        50000      // total nodes
#define RR        4          // relations
#define EE        1000000    // edges
#define IN_C      128
#define HIDC      128
#define OUTC      64
#define NBASIS    10
#define NSEG      (RR * NN)  // 200000

// ---------------------------------------------------------------------------
// W[r] = sum_b comp[r,b] * basis[b]
__global__ void wcomb_k(const float* __restrict__ comp,
                        const float* __restrict__ basis,
                        float* __restrict__ W, int IO) {
    int r = blockIdx.y;
    int idx = blockIdx.x * 256 + threadIdx.x;
    if (idx >= IO) return;
    float acc = 0.f;
#pragma unroll
    for (int b = 0; b < NBASIS; ++b)
        acc += comp[r * NBASIS + b] * basis[(size_t)b * IO + idx];
    W[(size_t)r * IO + idx] = acc;
}

// ---------------------------------------------------------------------------
// Generic fp32 GEMM: C[M,OC] = A[M,K] @ W[K,OC] (+bias) (+addsrc)
template <int OC>
__global__ void gemm_k(const float* __restrict__ A,
                       const float* __restrict__ W,
                       const float* __restrict__ bias,
                       const float* __restrict__ addsrc,
                       float* __restrict__ C, int M, int K) {
    constexpr int TM  = 32;
    constexpr int NG  = 256 / OC;
    constexpr int RPT = TM / NG;

    const int z = blockIdx.z;
    const float* Wp = W + (size_t)z * K * OC;
    float* Cp = C + (size_t)z * (size_t)M * OC;

    const int tid  = threadIdx.x;
    const int o    = tid % OC;
    const int tg   = tid / OC;
    const int rbase = tg * RPT;
    const int row0 = blockIdx.x * TM;

    float acc[RPT];
#pragma unroll
    for (int i = 0; i < RPT; ++i) acc[i] = 0.f;

    __shared__ float4 As[TM][32];

    for (int kc = 0; kc < K; kc += 128) {
#pragma unroll
        for (int i = 0; i < 4; ++i) {
            int idx = tid + i * 256;
            int rr = idx >> 5;
            int cc = idx & 31;
            int grow = row0 + rr;
            float4 v = make_float4(0.f, 0.f, 0.f, 0.f);
            if (grow < M)
                v = *(const float4*)(A + (size_t)grow * K + kc + cc * 4);
            As[rr][cc] = v;
        }
        __syncthreads();

        for (int k4 = 0; k4 < 32; ++k4) {
            int k = kc + k4 * 4;
            float w0 = Wp[(size_t)(k + 0) * OC + o];
            float w1 = Wp[(size_t)(k + 1) * OC + o];
            float w2 = Wp[(size_t)(k + 2) * OC + o];
            float w3 = Wp[(size_t)(k + 3) * OC + o];
#pragma unroll
            for (int i = 0; i < RPT; ++i) {
                float4 a = As[rbase + i][k4];
                acc[i] = fmaf(a.x, w0,
                         fmaf(a.y, w1,
                         fmaf(a.z, w2,
                         fmaf(a.w, w3, acc[i]))));
            }
        }
        __syncthreads();
    }

#pragma unroll
    for (int i = 0; i < RPT; ++i) {
        int grow = row0 + rbase + i;
        if (grow < M) {
            float v = acc[i];
            if (bias)   v += bias[o];
            if (addsrc) v += addsrc[(size_t)grow * OC + o];
            Cp[(size_t)grow * OC + o] = v;
        }
    }
}

// ---------------------------------------------------------------------------
// CSR build: counts -> exclusive scan -> cursor fill
__global__ void count_k(const int* __restrict__ et, const int* __restrict__ dstA,
                        int* __restrict__ cnt, int E) {
    int e = blockIdx.x * 256 + threadIdx.x;
    if (e < E) atomicAdd(&cnt[et[e] * NN + dstA[e]], 1);
}

#define SCAN_B 256
#define SCAN_I 8
#define SCAN_T (SCAN_B * SCAN_I)   // 2048 elems per block

__global__ void scan1_k(const int* __restrict__ in, int* __restrict__ out,
                        int* __restrict__ bsum, int n) {
    __shared__ int sm[SCAN_B];
    int b = blockIdx.x;
    int t = threadIdx.x;
    int basei = b * SCAN_T + t * SCAN_I;
    int v[SCAN_I]; int s = 0;
#pragma unroll
    for (int i = 0; i < SCAN_I; ++i) {
        int idx = basei + i;
        v[i] = (idx < n) ? in[idx] : 0;
        s += v[i];
    }
    sm[t] = s; __syncthreads();
    for (int off = 1; off < SCAN_B; off <<= 1) {
        int x = (t >= off) ? sm[t - off] : 0;
        __syncthreads();
        sm[t] += x;
        __syncthreads();
    }
    int run = (t > 0) ? sm[t - 1] : 0;   // exclusive base for this thread
    if (t == SCAN_B - 1) bsum[b] = sm[t];
#pragma unroll
    for (int i = 0; i < SCAN_I; ++i) {
        int idx = basei + i;
        if (idx < n) out[idx] = run;
        run += v[i];
    }
}

__global__ void scan2_k(int* __restrict__ bsum, int nb) {
    __shared__ int sm[256];
    int t = threadIdx.x;
    int v = (t < nb) ? bsum[t] : 0;
    sm[t] = v; __syncthreads();
    for (int off = 1; off < 256; off <<= 1) {
        int x = (t >= off) ? sm[t - off] : 0;
        __syncthreads();
        sm[t] += x;
        __syncthreads();
    }
    if (t < nb) bsum[t] = sm[t] - v;    // exclusive
}

__global__ void scan3_k(int* __restrict__ out, const int* __restrict__ bsum, int n) {
    int i = blockIdx.x * 256 + threadIdx.x;
    if (i < n) out[i] += bsum[i / SCAN_T];
}

// inv weight per segment + cursor init
__global__ void invcur_k(const int* __restrict__ cnt, const int* __restrict__ base,
                         float* __restrict__ inv, int* __restrict__ cursor, int n) {
    int i = blockIdx.x * 256 + threadIdx.x;
    if (i < n) {
        inv[i] = 1.0f / fmaxf((float)cnt[i], 1.0f);
        cursor[i] = base[i];
    }
}

__global__ void fill_k(const int* __restrict__ et, const int* __restrict__ srcA,
                       const int* __restrict__ dstA, int* __restrict__ cursor,
                       int* __restrict__ sorted, int E) {
    int e = blockIdx.x * 256 + threadIdx.x;
    if (e < E) {
        int seg = et[e] * NN + dstA[e];
        int pos = atomicAdd(&cursor[seg], 1);
        sorted[pos] = srcA[e];
    }
}

// ---------------------------------------------------------------------------
// Gather aggregation: one wave per dst node.
// out[d] = sum_r inv[r,d] * sum_{e in seg(r,d)} h[r, src_e]
// C=128: each lane holds float2; C=64: each lane holds float.
__global__ __launch_bounds__(256) void gather128_k(
    const float* __restrict__ h, const int* __restrict__ sorted,
    const int* __restrict__ base, const int* __restrict__ segend,
    const float* __restrict__ inv, float* __restrict__ out) {
    int w = (blockIdx.x * 256 + threadIdx.x) >> 6;   // dst node
    int lane = threadIdx.x & 63;
    if (w >= NN) return;
    float2 acc = make_float2(0.f, 0.f);
#pragma unroll
    for (int r = 0; r < RR; ++r) {
        int seg = r * NN + w;
        int s0 = base[seg], s1 = segend[seg];
        float wt = inv[seg];
        const float* hp = h + (size_t)r * NN * 128;
        for (int i = s0; i < s1; ++i) {
            int s = sorted[i];
            float2 v = ((const float2*)(hp + (size_t)s * 128))[lane];
            acc.x += v.x * wt;
            acc.y += v.y * wt;
        }
    }
    ((float2*)(out + (size_t)w * 128))[lane] = acc;
}

__global__ __launch_bounds__(256) void gather64_k(
    const float* __restrict__ h, const int* __restrict__ sorted,
    const int* __restrict__ base, const int* __restrict__ segend,
    const float* __restrict__ inv, float* __restrict__ out) {
    int w = (blockIdx.x * 256 + threadIdx.x) >> 6;
    int lane = threadIdx.x & 63;
    if (w >= NN) return;
    float acc = 0.f;
#pragma unroll
    for (int r = 0; r < RR; ++r) {
        int seg = r * NN + w;
        int s0 = base[seg], s1 = segend[seg];
        float wt = inv[seg];
        const float* hp = h + (size_t)r * NN * 64;
        for (int i = s0; i < s1; ++i) {
            int s = sorted[i];
            acc += hp[(size_t)s * 64 + lane] * wt;
        }
    }
    out[(size_t)w * 64 + lane] = acc;
}

// ---------------------------------------------------------------------------
extern "C" void kernel_launch(void* const* d_in, const int* in_sizes, int n_in,
                              void* d_out, int out_size, void* d_ws, size_t ws_size,
                              hipStream_t stream) {
    const float* x_mirna = (const float*)d_in[0];
    const float* x_gene  = (const float*)d_in[1];
    const int*   eidx    = (const int*)d_in[2];
    const int*   etype   = (const int*)d_in[3];
    const float* lin_w_m = (const float*)d_in[4];
    const float* lin_b_m = (const float*)d_in[5];
    const float* lin_w_g = (const float*)d_in[6];
    const float* lin_b_g = (const float*)d_in[7];
    const float* comp1   = (const float*)d_in[8];
    const float* basis1  = (const float*)d_in[9];
    const float* root1   = (const float*)d_in[10];
    const float* bias1   = (const float*)d_in[11];
    const float* comp2   = (const float*)d_in[12];
    const float* basis2  = (const float*)d_in[13];
    const float* root2   = (const float*)d_in[14];
    const float* bias2   = (const float*)d_in[15];

    const int* srcA = eidx;
    const int* dstA = eidx + EE;

    // workspace layout
    float* ws = (float*)d_ws;
    size_t off = 0;
    float* W1  = ws + off; off += (size_t)RR * IN_C * HIDC;
    float* W2  = ws + off; off += (size_t)RR * HIDC * OUTC;
    float* x0  = ws + off; off += (size_t)NN * IN_C;
    float* h1  = ws + off; off += (size_t)RR * NN * HIDC;
    float* h2  = ws + off; off += (size_t)RR * NN * OUTC;
    float* x1  = ws + off; off += (size_t)NN * HIDC;
    float* inv = ws + off; off += NSEG;
    int* cnt    = (int*)(ws + off); off += NSEG;
    int* base   = (int*)(ws + off); off += NSEG;
    int* cursor = (int*)(ws + off); off += NSEG;   // == segend after fill
    int* bsum   = (int*)(ws + off); off += 256;
    int* sorted = (int*)(ws + off); off += EE;

    float* outp = (float*)d_out;

    // CSR build
    hipMemsetAsync(cnt, 0, NSEG * sizeof(int), stream);

    // relation weights
    wcomb_k<<<dim3((IN_C * HIDC + 255) / 256, RR), 256, 0, stream>>>(comp1, basis1, W1, IN_C * HIDC);
    wcomb_k<<<dim3((HIDC * OUTC + 255) / 256, RR), 256, 0, stream>>>(comp2, basis2, W2, HIDC * OUTC);

    // input projections -> x0
    gemm_k<IN_C><<<dim3((NUM_MIRNA + 31) / 32, 1, 1), 256, 0, stream>>>(
        x_mirna, lin_w_m, lin_b_m, nullptr, x0, NUM_MIRNA, 256);
    gemm_k<IN_C><<<dim3((NUM_GENE + 31) / 32, 1, 1), 256, 0, stream>>>(
        x_gene, lin_w_g, lin_b_g, nullptr, x0 + (size_t)NUM_MIRNA * IN_C, NUM_GENE, 512);

    // counts -> exclusive scan -> fill
    count_k<<<(EE + 255) / 256, 256, 0, stream>>>(etype, dstA, cnt, EE);
    int nb = (NSEG + SCAN_T - 1) / SCAN_T;   // 98
    scan1_k<<<nb, SCAN_B, 0, stream>>>(cnt, base, bsum, NSEG);
    scan2_k<<<1, 256, 0, stream>>>(bsum, nb);
    scan3_k<<<(NSEG + 255) / 256, 256, 0, stream>>>(base, bsum, NSEG);
    invcur_k<<<(NSEG + 255) / 256, 256, 0, stream>>>(cnt, base, inv, cursor, NSEG);
    fill_k<<<(EE + 255) / 256, 256, 0, stream>>>(etype, srcA, dstA, cursor, sorted, EE);

    // layer 1
    gemm_k<HIDC><<<dim3((NN + 31) / 32, 1, RR), 256, 0, stream>>>(
        x0, W1, nullptr, nullptr, h1, NN, IN_C);
    gather128_k<<<(NN * 64 + 255) / 256, 256, 0, stream>>>(h1, sorted, base, cursor, inv, x1);
    gemm_k<HIDC><<<dim3((NN + 31) / 32, 1, 1), 256, 0, stream>>>(
        x0, root1, bias1, x1, x1, NN, IN_C);

    // layer 2
    gemm_k<OUTC><<<dim3((NN + 31) / 32, 1, RR), 256, 0, stream>>>(
        x1, W2, nullptr, nullptr, h2, NN, HIDC);
    gather64_k<<<(NN * 64 + 255) / 256, 256, 0, stream>>>(h2, sorted, base, cursor, inv, outp);
    gemm_k<OUTC><<<dim3((NN + 31) / 32, 1, 1), 256, 0, stream>>>(
        x1, root2, bias2, outp, outp, NN, HIDC);
}

// Round 3
// 569.141 us; speedup vs baseline: 2.0253x; 1.3478x over previous
//
#include <hip/hip_runtime.h>
#include <hip/hip_bf16.h>

// Problem constants (match reference)
#define NUM_MIRNA 20000
#define NUM_GENE  30000
#define NN        50000      // total nodes
#define RR        4          // relations
#define EE        1000000    // edges
#define IN_C      128
#define HIDC      128
#define OUTC      64
#define NBASIS    10
#define NSEG      (RR * NN)  // 200000

typedef __attribute__((ext_vector_type(8))) short bf16x8;
typedef __attribute__((ext_vector_type(4))) float f32x4;

__device__ inline ushort f2bf(float x) {
    uint u = __float_as_uint(x);
    uint r = u + 0x7fffu + ((u >> 16) & 1u);
    return (ushort)(r >> 16);
}
__device__ inline float bf2f(ushort b) {
    return __uint_as_float((uint)b << 16);
}

// ---------------------------------------------------------------------------
// fp32 -> bf16 (4 elems/thread)
__global__ void cvt_k(const float* __restrict__ in, ushort* __restrict__ out, int n4) {
    int i = blockIdx.x * 256 + threadIdx.x;
    if (i >= n4) return;
    float4 v = ((const float4*)in)[i];
    ushort4 o;
    o.x = f2bf(v.x); o.y = f2bf(v.y); o.z = f2bf(v.z); o.w = f2bf(v.w);
    ((ushort4*)out)[i] = o;
}

// transpose+cast: Wt[o][k] = bf16(W[k][o]);  W: [K][OC]
__global__ void tcast_k(const float* __restrict__ W, ushort* __restrict__ Wt,
                        int K, int OC) {
    int idx = blockIdx.x * 256 + threadIdx.x;
    if (idx >= K * OC) return;
    int o = idx / K, k = idx % K;
    Wt[idx] = f2bf(W[(size_t)k * OC + o]);
}

// basis combine + transpose + cast: Wt[r][o][i] = bf16(sum_b comp[r,b]*basis[b][i][o])
// basis: [NB][I][O], grid.y = r
__global__ void wcombT_k(const float* __restrict__ comp, const float* __restrict__ basis,
                         ushort* __restrict__ Wt, int I, int O) {
    int r = blockIdx.y;
    int idx = blockIdx.x * 256 + threadIdx.x;  // over O*I, o-major
    if (idx >= O * I) return;
    int o = idx / I, i = idx % I;
    float acc = 0.f;
#pragma unroll
    for (int b = 0; b < NBASIS; ++b)
        acc += comp[r * NBASIS + b] * basis[((size_t)b * I + i) * O + o];
    Wt[(size_t)r * O * I + idx] = f2bf(acc);
}

// ---------------------------------------------------------------------------
// MFMA bf16 GEMM: C[z][M][OC] = A[M][K](bf16) @ Wt[z][OC][K](bf16)^T (+bias)(+addsrc)
// Block 256 thr = 4 waves; each wave: MT=2 row-tiles (32 rows) x NT col-tiles.
template <int NT, bool OUT_BF16>
__global__ __launch_bounds__(256) void mgemm_k(
    const ushort* __restrict__ A, const ushort* __restrict__ Wt,
    const float* __restrict__ bias, const float* __restrict__ addsrc,
    void* __restrict__ Cout, int M, int K)
{
    constexpr int MT = 2;
    constexpr int OC = NT * 16;
    const int z = blockIdx.z;
    const ushort* Wz = Wt + (size_t)z * OC * K;
    const int lane = threadIdx.x & 63;
    const int wid  = threadIdx.x >> 6;
    const int l15  = lane & 15;
    const int lg   = lane >> 4;
    const int rowBase = blockIdx.x * (4 * MT * 16) + wid * (MT * 16);

    f32x4 acc[MT][NT];
#pragma unroll
    for (int mt = 0; mt < MT; ++mt)
#pragma unroll
        for (int nt = 0; nt < NT; ++nt)
            acc[mt][nt] = (f32x4){0.f, 0.f, 0.f, 0.f};

    int ar[MT];
#pragma unroll
    for (int mt = 0; mt < MT; ++mt) {
        int r = rowBase + mt * 16 + l15;
        ar[mt] = (r < M) ? r : (M - 1);
    }

    for (int kc = 0; kc < K; kc += 32) {
        int ka = kc + lg * 8;
        bf16x8 a[MT];
#pragma unroll
        for (int mt = 0; mt < MT; ++mt)
            a[mt] = *(const bf16x8*)(A + (size_t)ar[mt] * K + ka);
#pragma unroll
        for (int nt = 0; nt < NT; ++nt) {
            bf16x8 b = *(const bf16x8*)(Wz + (size_t)(nt * 16 + l15) * K + ka);
#pragma unroll
            for (int mt = 0; mt < MT; ++mt)
                acc[mt][nt] = __builtin_amdgcn_mfma_f32_16x16x32_bf16(
                    a[mt], b, acc[mt][nt], 0, 0, 0);
        }
    }

#pragma unroll
    for (int nt = 0; nt < NT; ++nt) {
        int n = nt * 16 + l15;
        float bv = bias ? bias[n] : 0.f;
#pragma unroll
        for (int mt = 0; mt < MT; ++mt) {
#pragma unroll
            for (int q = 0; q < 4; ++q) {
                int m = rowBase + mt * 16 + lg * 4 + q;
                if (m < M) {
                    float v = acc[mt][nt][q] + bv;
                    if (addsrc) v += addsrc[(size_t)m * OC + n];
                    size_t off = (size_t)z * M * OC + (size_t)m * OC + n;
                    if (OUT_BF16) ((ushort*)Cout)[off] = f2bf(v);
                    else          ((float*)Cout)[off]  = v;
                }
            }
        }
    }
}

// ---------------------------------------------------------------------------
// CSR build: counts -> exclusive scan -> cursor fill
__global__ void count_k(const int* __restrict__ et, const int* __restrict__ dstA,
                        int* __restrict__ cnt, int E) {
    int e = blockIdx.x * 256 + threadIdx.x;
    if (e < E) atomicAdd(&cnt[et[e] * NN + dstA[e]], 1);
}

#define SCAN_B 256
#define SCAN_I 8
#define SCAN_T (SCAN_B * SCAN_I)   // 2048 elems per block

__global__ void scan1_k(const int* __restrict__ in, int* __restrict__ out,
                        int* __restrict__ bsum, int n) {
    __shared__ int sm[SCAN_B];
    int b = blockIdx.x;
    int t = threadIdx.x;
    int basei = b * SCAN_T + t * SCAN_I;
    int v[SCAN_I]; int s = 0;
#pragma unroll
    for (int i = 0; i < SCAN_I; ++i) {
        int idx = basei + i;
        v[i] = (idx < n) ? in[idx] : 0;
        s += v[i];
    }
    sm[t] = s; __syncthreads();
    for (int off = 1; off < SCAN_B; off <<= 1) {
        int x = (t >= off) ? sm[t - off] : 0;
        __syncthreads();
        sm[t] += x;
        __syncthreads();
    }
    int run = (t > 0) ? sm[t - 1] : 0;
    if (t == SCAN_B - 1) bsum[b] = sm[t];
#pragma unroll
    for (int i = 0; i < SCAN_I; ++i) {
        int idx = basei + i;
        if (idx < n) out[idx] = run;
        run += v[i];
    }
}

__global__ void scan2_k(int* __restrict__ bsum, int nb) {
    __shared__ int sm[256];
    int t = threadIdx.x;
    int v = (t < nb) ? bsum[t] : 0;
    sm[t] = v; __syncthreads();
    for (int off = 1; off < 256; off <<= 1) {
        int x = (t >= off) ? sm[t - off] : 0;
        __syncthreads();
        sm[t] += x;
        __syncthreads();
    }
    if (t < nb) bsum[t] = sm[t] - v;
}

__global__ void scan3_k(int* __restrict__ out, const int* __restrict__ bsum, int n) {
    int i = blockIdx.x * 256 + threadIdx.x;
    if (i < n) out[i] += bsum[i / SCAN_T];
}

__global__ void invcur_k(const int* __restrict__ cnt, const int* __restrict__ base,
                         float* __restrict__ inv, int* __restrict__ cursor, int n) {
    int i = blockIdx.x * 256 + threadIdx.x;
    if (i < n) {
        inv[i] = 1.0f / fmaxf((float)cnt[i], 1.0f);
        cursor[i] = base[i];
    }
}

__global__ void fill_k(const int* __restrict__ et, const int* __restrict__ srcA,
                       const int* __restrict__ dstA, int* __restrict__ cursor,
                       int* __restrict__ sorted, int E) {
    int e = blockIdx.x * 256 + threadIdx.x;
    if (e < E) {
        int seg = et[e] * NN + dstA[e];
        int pos = atomicAdd(&cursor[seg], 1);
        sorted[pos] = srcA[e];
    }
}

// ---------------------------------------------------------------------------
// Gather aggregation from bf16 h, one wave per dst node.
__global__ __launch_bounds__(256) void gather128_k(
    const ushort* __restrict__ h, const int* __restrict__ sorted,
    const int* __restrict__ base, const int* __restrict__ segend,
    const float* __restrict__ inv, float* __restrict__ out) {
    int w = (blockIdx.x * 256 + threadIdx.x) >> 6;
    int lane = threadIdx.x & 63;
    if (w >= NN) return;
    float2 acc = make_float2(0.f, 0.f);
#pragma unroll
    for (int r = 0; r < RR; ++r) {
        int seg = r * NN + w;
        int s0 = base[seg], s1 = segend[seg];
        float wt = inv[seg];
        const uint* hp = (const uint*)h + (size_t)r * NN * 64;  // 64 uints/row
        float2 part = make_float2(0.f, 0.f);
        for (int i = s0; i < s1; ++i) {
            uint v = hp[(size_t)sorted[i] * 64 + lane];
            part.x += bf2f((ushort)(v & 0xffffu));
            part.y += bf2f((ushort)(v >> 16));
        }
        acc.x += part.x * wt;
        acc.y += part.y * wt;
    }
    ((float2*)(out + (size_t)w * 128))[lane] = acc;
}

__global__ __launch_bounds__(256) void gather64_k(
    const ushort* __restrict__ h, const int* __restrict__ sorted,
    const int* __restrict__ base, const int* __restrict__ segend,
    const float* __restrict__ inv, float* __restrict__ out) {
    int w = (blockIdx.x * 256 + threadIdx.x) >> 6;
    int lane = threadIdx.x & 63;
    if (w >= NN) return;
    float acc = 0.f;
#pragma unroll
    for (int r = 0; r < RR; ++r) {
        int seg = r * NN + w;
        int s0 = base[seg], s1 = segend[seg];
        float wt = inv[seg];
        const ushort* hp = h + (size_t)r * NN * 64;
        float part = 0.f;
        for (int i = s0; i < s1; ++i)
            part += bf2f(hp[(size_t)sorted[i] * 64 + lane]);
        acc += part * wt;
    }
    out[(size_t)w * 64 + lane] = acc;
}

// ---------------------------------------------------------------------------
extern "C" void kernel_launch(void* const* d_in, const int* in_sizes, int n_in,
                              void* d_out, int out_size, void* d_ws, size_t ws_size,
                              hipStream_t stream) {
    const float* x_mirna = (const float*)d_in[0];
    const float* x_gene  = (const float*)d_in[1];
    const int*   eidx    = (const int*)d_in[2];
    const int*   etype   = (const int*)d_in[3];
    const float* lin_w_m = (const float*)d_in[4];
    const float* lin_b_m = (const float*)d_in[5];
    const float* lin_w_g = (const float*)d_in[6];
    const float* lin_b_g = (const float*)d_in[7];
    const float* comp1   = (const float*)d_in[8];
    const float* basis1  = (const float*)d_in[9];
    const float* root1   = (const float*)d_in[10];
    const float* bias1   = (const float*)d_in[11];
    const float* comp2   = (const float*)d_in[12];
    const float* basis2  = (const float*)d_in[13];
    const float* root2   = (const float*)d_in[14];
    const float* bias2   = (const float*)d_in[15];

    const int* srcA = eidx;
    const int* dstA = eidx + EE;

    // workspace layout (bytes)
    char* p = (char*)d_ws;
    ushort* xmbf = (ushort*)p; p += (size_t)NUM_MIRNA * 256 * 2;
    ushort* xgbf = (ushort*)p; p += (size_t)NUM_GENE * 512 * 2;
    ushort* x0bf = (ushort*)p; p += (size_t)NN * IN_C * 2;
    ushort* x1bf = (ushort*)p; p += (size_t)NN * HIDC * 2;
    ushort* h1bf = (ushort*)p; p += (size_t)RR * NN * HIDC * 2;
    ushort* h2bf = (ushort*)p; p += (size_t)RR * NN * OUTC * 2;
    ushort* Wtm  = (ushort*)p; p += (size_t)IN_C * 256 * 2;
    ushort* Wtg  = (ushort*)p; p += (size_t)IN_C * 512 * 2;
    ushort* Wt1  = (ushort*)p; p += (size_t)RR * HIDC * IN_C * 2;
    ushort* Wtr1 = (ushort*)p; p += (size_t)HIDC * IN_C * 2;
    ushort* Wt2  = (ushort*)p; p += (size_t)RR * OUTC * HIDC * 2;
    ushort* Wtr2 = (ushort*)p; p += (size_t)OUTC * HIDC * 2;
    float* x1    = (float*)p;  p += (size_t)NN * HIDC * 4;
    float* inv   = (float*)p;  p += (size_t)NSEG * 4;
    int* cnt     = (int*)p;    p += (size_t)NSEG * 4;
    int* base    = (int*)p;    p += (size_t)NSEG * 4;
    int* cursor  = (int*)p;    p += (size_t)NSEG * 4;
    int* bsum    = (int*)p;    p += 1024;
    int* sorted  = (int*)p;    p += (size_t)EE * 4;

    float* outp = (float*)d_out;

    hipMemsetAsync(cnt, 0, NSEG * sizeof(int), stream);

    // bf16 converts of inputs
    cvt_k<<<(NUM_MIRNA * 256 / 4 + 255) / 256, 256, 0, stream>>>(x_mirna, xmbf, NUM_MIRNA * 256 / 4);
    cvt_k<<<(NUM_GENE * 512 / 4 + 255) / 256, 256, 0, stream>>>(x_gene, xgbf, NUM_GENE * 512 / 4);

    // packed transposed weights
    tcast_k<<<(256 * IN_C + 255) / 256, 256, 0, stream>>>(lin_w_m, Wtm, 256, IN_C);
    tcast_k<<<(512 * IN_C + 255) / 256, 256, 0, stream>>>(lin_w_g, Wtg, 512, IN_C);
    tcast_k<<<(IN_C * HIDC + 255) / 256, 256, 0, stream>>>(root1, Wtr1, IN_C, HIDC);
    tcast_k<<<(HIDC * OUTC + 255) / 256, 256, 0, stream>>>(root2, Wtr2, HIDC, OUTC);
    wcombT_k<<<dim3((HIDC * IN_C + 255) / 256, RR), 256, 0, stream>>>(comp1, basis1, Wt1, IN_C, HIDC);
    wcombT_k<<<dim3((OUTC * HIDC + 255) / 256, RR), 256, 0, stream>>>(comp2, basis2, Wt2, HIDC, OUTC);

    // CSR build
    count_k<<<(EE + 255) / 256, 256, 0, stream>>>(etype, dstA, cnt, EE);
    int nb = (NSEG + SCAN_T - 1) / SCAN_T;
    scan1_k<<<nb, SCAN_B, 0, stream>>>(cnt, base, bsum, NSEG);
    scan2_k<<<1, 256, 0, stream>>>(bsum, nb);
    scan3_k<<<(NSEG + 255) / 256, 256, 0, stream>>>(base, bsum, NSEG);
    invcur_k<<<(NSEG + 255) / 256, 256, 0, stream>>>(cnt, base, inv, cursor, NSEG);
    fill_k<<<(EE + 255) / 256, 256, 0, stream>>>(etype, srcA, dstA, cursor, sorted, EE);

    // input projections -> x0bf
    mgemm_k<8, true><<<dim3((NUM_MIRNA + 127) / 128, 1, 1), 256, 0, stream>>>(
        xmbf, Wtm, lin_b_m, nullptr, x0bf, NUM_MIRNA, 256);
    mgemm_k<8, true><<<dim3((NUM_GENE + 127) / 128, 1, 1), 256, 0, stream>>>(
        xgbf, Wtg, lin_b_g, nullptr, x0bf + (size_t)NUM_MIRNA * IN_C, NUM_GENE, 512);

    // layer 1
    mgemm_k<8, true><<<dim3((NN + 127) / 128, 1, RR), 256, 0, stream>>>(
        x0bf, Wt1, nullptr, nullptr, h1bf, NN, IN_C);
    gather128_k<<<(NN * 64 + 255) / 256, 256, 0, stream>>>(h1bf, sorted, base, cursor, inv, x1);
    mgemm_k<8, true><<<dim3((NN + 127) / 128, 1, 1), 256, 0, stream>>>(
        x0bf, Wtr1, bias1, x1, x1bf, NN, IN_C);

    // layer 2
    mgemm_k<4, true><<<dim3((NN + 127) / 128, 1, RR), 256, 0, stream>>>(
        x1bf, Wt2, nullptr, nullptr, h2bf, NN, HIDC);
    gather64_k<<<(NN * 64 + 255) / 256, 256, 0, stream>>>(h2bf, sorted, base, cursor, inv, outp);
    mgemm_k<4, false><<<dim3((NN + 127) / 128, 1, 1), 256, 0, stream>>>(
        x1bf, Wtr2, bias2, outp, outp, NN, HIDC);
}

// Round 4
// 497.500 us; speedup vs baseline: 2.3169x; 1.1440x over previous
//
#include <hip/hip_runtime.h>
#include <hip/hip_bf16.h>

// Problem constants (match reference)
#define NUM_MIRNA 20000
#define NUM_GENE  30000
#define NN        50000      // total nodes
#define RR        4          // relations
#define EE        1000000    // edges
#define IN_C      128
#define HIDC      128
#define OUTC      64
#define NBASIS    10
#define NSEG      (RR * NN)  // 200000
#define KFUSE     640        // 4*128 aggregated blocks + 128 root block

typedef __attribute__((ext_vector_type(8))) short bf16x8;
typedef __attribute__((ext_vector_type(4))) float f32x4;

__device__ inline ushort f2bf(float x) {
    uint u = __float_as_uint(x);
    uint r = u + 0x7fffu + ((u >> 16) & 1u);
    return (ushort)(r >> 16);
}
__device__ inline float bf2f(ushort b) {
    return __uint_as_float((uint)b << 16);
}
__device__ inline uint pack2bf(float lo, float hi) {
    return (uint)f2bf(lo) | ((uint)f2bf(hi) << 16);
}

// ---------------------------------------------------------------------------
// fp32 -> bf16 (4 elems/thread)
__global__ void cvt_k(const float* __restrict__ in, ushort* __restrict__ out, int n4) {
    int i = blockIdx.x * 256 + threadIdx.x;
    if (i >= n4) return;
    float4 v = ((const float4*)in)[i];
    ushort4 o;
    o.x = f2bf(v.x); o.y = f2bf(v.y); o.z = f2bf(v.z); o.w = f2bf(v.w);
    ((ushort4*)out)[i] = o;
}

// transpose+cast: Wt[o][k] = bf16(W[k][o]);  W: [K][OC]  (input projections)
__global__ void tcast_k(const float* __restrict__ W, ushort* __restrict__ Wt,
                        int K, int OC) {
    int idx = blockIdx.x * 256 + threadIdx.x;
    if (idx >= K * OC) return;
    int o = idx / K, k = idx % K;
    Wt[idx] = f2bf(W[(size_t)k * OC + o]);
}

// Build stacked transposed fused weight: Wt[o][k], k in [0,640)
// k<512: relation block r=k>>7, i=k&127:  sum_b comp[r,b]*basis[b,i,o]
// k>=512: root[k-512][o]
__global__ void buildW_k(const float* __restrict__ comp, const float* __restrict__ basis,
                         const float* __restrict__ root, ushort* __restrict__ Wt, int O) {
    int idx = blockIdx.x * 256 + threadIdx.x;
    if (idx >= O * KFUSE) return;
    int o = idx / KFUSE, k = idx % KFUSE;
    float acc;
    if (k < 512) {
        int r = k >> 7, i = k & 127;
        acc = 0.f;
#pragma unroll
        for (int b = 0; b < NBASIS; ++b)
            acc += comp[r * NBASIS + b] * basis[((size_t)b * 128 + i) * O + o];
    } else {
        acc = root[(size_t)(k - 512) * O + o];
    }
    Wt[idx] = f2bf(acc);
}

// ---------------------------------------------------------------------------
// MFMA bf16 GEMM: C[M][OC] = A[M][K](bf16) @ Wt[OC][K](bf16)^T (+bias)
// Block 256 thr = 4 waves; each wave: MT=2 row-tiles (32 rows) x NT col-tiles.
template <int NT, bool OUT_BF16>
__global__ __launch_bounds__(256) void mgemm_k(
    const ushort* __restrict__ A, const ushort* __restrict__ Wt,
    const float* __restrict__ bias, void* __restrict__ Cout, int M, int K)
{
    constexpr int MT = 2;
    constexpr int OC = NT * 16;
    const int lane = threadIdx.x & 63;
    const int wid  = threadIdx.x >> 6;
    const int l15  = lane & 15;
    const int lg   = lane >> 4;
    const int rowBase = blockIdx.x * (4 * MT * 16) + wid * (MT * 16);

    f32x4 acc[MT][NT];
#pragma unroll
    for (int mt = 0; mt < MT; ++mt)
#pragma unroll
        for (int nt = 0; nt < NT; ++nt)
            acc[mt][nt] = (f32x4){0.f, 0.f, 0.f, 0.f};

    int ar[MT];
#pragma unroll
    for (int mt = 0; mt < MT; ++mt) {
        int r = rowBase + mt * 16 + l15;
        ar[mt] = (r < M) ? r : (M - 1);
    }

    for (int kc = 0; kc < K; kc += 32) {
        int ka = kc + lg * 8;
        bf16x8 a[MT];
#pragma unroll
        for (int mt = 0; mt < MT; ++mt)
            a[mt] = *(const bf16x8*)(A + (size_t)ar[mt] * K + ka);
#pragma unroll
        for (int nt = 0; nt < NT; ++nt) {
            bf16x8 b = *(const bf16x8*)(Wt + (size_t)(nt * 16 + l15) * K + ka);
#pragma unroll
            for (int mt = 0; mt < MT; ++mt)
                acc[mt][nt] = __builtin_amdgcn_mfma_f32_16x16x32_bf16(
                    a[mt], b, acc[mt][nt], 0, 0, 0);
        }
    }

#pragma unroll
    for (int nt = 0; nt < NT; ++nt) {
        int n = nt * 16 + l15;
        float bv = bias ? bias[n] : 0.f;
#pragma unroll
        for (int mt = 0; mt < MT; ++mt) {
#pragma unroll
            for (int q = 0; q < 4; ++q) {
                int m = rowBase + mt * 16 + lg * 4 + q;
                if (m < M) {
                    float v = acc[mt][nt][q] + bv;
                    size_t off = (size_t)m * OC + n;
                    if (OUT_BF16) ((ushort*)Cout)[off] = f2bf(v);
                    else          ((float*)Cout)[off]  = v;
                }
            }
        }
    }
}

// ---------------------------------------------------------------------------
// CSR build: counts -> exclusive scan -> cursor fill
__global__ void count_k(const int* __restrict__ et, const int* __restrict__ dstA,
                        int* __restrict__ cnt, int E) {
    int e = blockIdx.x * 256 + threadIdx.x;
    if (e < E) atomicAdd(&cnt[et[e] * NN + dstA[e]], 1);
}

#define SCAN_B 256
#define SCAN_I 8
#define SCAN_T (SCAN_B * SCAN_I)   // 2048 elems per block

__global__ void scan1_k(const int* __restrict__ in, int* __restrict__ out,
                        int* __restrict__ bsum, int n) {
    __shared__ int sm[SCAN_B];
    int b = blockIdx.x;
    int t = threadIdx.x;
    int basei = b * SCAN_T + t * SCAN_I;
    int v[SCAN_I]; int s = 0;
#pragma unroll
    for (int i = 0; i < SCAN_I; ++i) {
        int idx = basei + i;
        v[i] = (idx < n) ? in[idx] : 0;
        s += v[i];
    }
    sm[t] = s; __syncthreads();
    for (int off = 1; off < SCAN_B; off <<= 1) {
        int x = (t >= off) ? sm[t - off] : 0;
        __syncthreads();
        sm[t] += x;
        __syncthreads();
    }
    int run = (t > 0) ? sm[t - 1] : 0;
    if (t == SCAN_B - 1) bsum[b] = sm[t];
#pragma unroll
    for (int i = 0; i < SCAN_I; ++i) {
        int idx = basei + i;
        if (idx < n) out[idx] = run;
        run += v[i];
    }
}

__global__ void scan2_k(int* __restrict__ bsum, int nb) {
    __shared__ int sm[256];
    int t = threadIdx.x;
    int v = (t < nb) ? bsum[t] : 0;
    sm[t] = v; __syncthreads();
    for (int off = 1; off < 256; off <<= 1) {
        int x = (t >= off) ? sm[t - off] : 0;
        __syncthreads();
        sm[t] += x;
        __syncthreads();
    }
    if (t < nb) bsum[t] = sm[t] - v;
}

__global__ void scan3_k(int* __restrict__ out, const int* __restrict__ bsum, int n) {
    int i = blockIdx.x * 256 + threadIdx.x;
    if (i < n) out[i] += bsum[i / SCAN_T];
}

__global__ void invcur_k(const int* __restrict__ cnt, const int* __restrict__ base,
                         float* __restrict__ inv, int* __restrict__ cursor, int n) {
    int i = blockIdx.x * 256 + threadIdx.x;
    if (i < n) {
        inv[i] = 1.0f / fmaxf((float)cnt[i], 1.0f);
        cursor[i] = base[i];
    }
}

__global__ void fill_k(const int* __restrict__ et, const int* __restrict__ srcA,
                       const int* __restrict__ dstA, int* __restrict__ cursor,
                       int* __restrict__ sorted, int E) {
    int e = blockIdx.x * 256 + threadIdx.x;
    if (e < E) {
        int seg = et[e] * NN + dstA[e];
        int pos = atomicAdd(&cursor[seg], 1);
        sorted[pos] = srcA[e];
    }
}

// ---------------------------------------------------------------------------
// Aggregate x rows per (relation, dst) into fused-K matrix S:
// S[d][r*128 + c] = inv[r,d] * sum_{e in seg(r,d)} x[src_e][c]   (bf16)
// S[d][512 + c]   = x[d][c]
// One wave per dst node; lane owns 2 bf16 columns (one uint).
__global__ __launch_bounds__(256) void gatherS_k(
    const ushort* __restrict__ x, const int* __restrict__ sorted,
    const int* __restrict__ base, const int* __restrict__ segend,
    const float* __restrict__ inv, ushort* __restrict__ S)
{
    int d = (blockIdx.x * 256 + threadIdx.x) >> 6;
    int lane = threadIdx.x & 63;
    if (d >= NN) return;
    const uint* xp = (const uint*)x;   // 64 uints per 128-col row
    uint* Sp = (uint*)S;               // 320 uints per row
#pragma unroll
    for (int r = 0; r < RR; ++r) {
        int seg = r * NN + d;
        int s0 = base[seg], s1 = segend[seg];
        float wt = inv[seg];
        float ax = 0.f, ay = 0.f;
        for (int i = s0; i < s1; ++i) {
            uint v = xp[(size_t)sorted[i] * 64 + lane];
            ax += bf2f((ushort)(v & 0xffffu));
            ay += bf2f((ushort)(v >> 16));
        }
        Sp[(size_t)d * 320 + r * 64 + lane] = pack2bf(ax * wt, ay * wt);
    }
    // root block: copy own row
    Sp[(size_t)d * 320 + 256 + lane] = xp[(size_t)d * 64 + lane];
}

// ---------------------------------------------------------------------------
extern "C" void kernel_launch(void* const* d_in, const int* in_sizes, int n_in,
                              void* d_out, int out_size, void* d_ws, size_t ws_size,
                              hipStream_t stream) {
    const float* x_mirna = (const float*)d_in[0];
    const float* x_gene  = (const float*)d_in[1];
    const int*   eidx    = (const int*)d_in[2];
    const int*   etype   = (const int*)d_in[3];
    const float* lin_w_m = (const float*)d_in[4];
    const float* lin_b_m = (const float*)d_in[5];
    const float* lin_w_g = (const float*)d_in[6];
    const float* lin_b_g = (const float*)d_in[7];
    const float* comp1   = (const float*)d_in[8];
    const float* basis1  = (const float*)d_in[9];
    const float* root1   = (const float*)d_in[10];
    const float* bias1   = (const float*)d_in[11];
    const float* comp2   = (const float*)d_in[12];
    const float* basis2  = (const float*)d_in[13];
    const float* root2   = (const float*)d_in[14];
    const float* bias2   = (const float*)d_in[15];

    const int* srcA = eidx;
    const int* dstA = eidx + EE;

    // workspace layout (bytes)
    char* p = (char*)d_ws;
    ushort* xmbf = (ushort*)p; p += (size_t)NUM_MIRNA * 256 * 2;
    ushort* xgbf = (ushort*)p; p += (size_t)NUM_GENE * 512 * 2;
    ushort* x0bf = (ushort*)p; p += (size_t)NN * IN_C * 2;
    ushort* x1bf = (ushort*)p; p += (size_t)NN * HIDC * 2;
    ushort* S    = (ushort*)p; p += (size_t)NN * KFUSE * 2;     // 64 MB
    ushort* Wtm  = (ushort*)p; p += (size_t)IN_C * 256 * 2;
    ushort* Wtg  = (ushort*)p; p += (size_t)IN_C * 512 * 2;
    ushort* Wt1s = (ushort*)p; p += (size_t)HIDC * KFUSE * 2;
    ushort* Wt2s = (ushort*)p; p += (size_t)OUTC * KFUSE * 2;
    float* inv   = (float*)p;  p += (size_t)NSEG * 4;
    int* cnt     = (int*)p;    p += (size_t)NSEG * 4;
    int* base    = (int*)p;    p += (size_t)NSEG * 4;
    int* cursor  = (int*)p;    p += (size_t)NSEG * 4;
    int* bsum    = (int*)p;    p += 1024;
    int* sorted  = (int*)p;    p += (size_t)EE * 4;

    float* outp = (float*)d_out;

    hipMemsetAsync(cnt, 0, NSEG * sizeof(int), stream);

    // bf16 converts of inputs
    cvt_k<<<(NUM_MIRNA * 256 / 4 + 255) / 256, 256, 0, stream>>>(x_mirna, xmbf, NUM_MIRNA * 256 / 4);
    cvt_k<<<(NUM_GENE * 512 / 4 + 255) / 256, 256, 0, stream>>>(x_gene, xgbf, NUM_GENE * 512 / 4);

    // packed transposed weights
    tcast_k<<<(256 * IN_C + 255) / 256, 256, 0, stream>>>(lin_w_m, Wtm, 256, IN_C);
    tcast_k<<<(512 * IN_C + 255) / 256, 256, 0, stream>>>(lin_w_g, Wtg, 512, IN_C);
    buildW_k<<<(HIDC * KFUSE + 255) / 256, 256, 0, stream>>>(comp1, basis1, root1, Wt1s, HIDC);
    buildW_k<<<(OUTC * KFUSE + 255) / 256, 256, 0, stream>>>(comp2, basis2, root2, Wt2s, OUTC);

    // CSR build
    count_k<<<(EE + 255) / 256, 256, 0, stream>>>(etype, dstA, cnt, EE);
    int nb = (NSEG + SCAN_T - 1) / SCAN_T;
    scan1_k<<<nb, SCAN_B, 0, stream>>>(cnt, base, bsum, NSEG);
    scan2_k<<<1, 256, 0, stream>>>(bsum, nb);
    scan3_k<<<(NSEG + 255) / 256, 256, 0, stream>>>(base, bsum, NSEG);
    invcur_k<<<(NSEG + 255) / 256, 256, 0, stream>>>(cnt, base, inv, cursor, NSEG);
    fill_k<<<(EE + 255) / 256, 256, 0, stream>>>(etype, srcA, dstA, cursor, sorted, EE);

    // input projections -> x0bf
    mgemm_k<8, true><<<dim3((NUM_MIRNA + 127) / 128), 256, 0, stream>>>(
        xmbf, Wtm, lin_b_m, x0bf, NUM_MIRNA, 256);
    mgemm_k<8, true><<<dim3((NUM_GENE + 127) / 128), 256, 0, stream>>>(
        xgbf, Wtg, lin_b_g, x0bf + (size_t)NUM_MIRNA * IN_C, NUM_GENE, 512);

    // layer 1: aggregate x0 -> S, then fused [rel GEMMs + root + bias]
    gatherS_k<<<(NN * 64 + 255) / 256, 256, 0, stream>>>(x0bf, sorted, base, cursor, inv, S);
    mgemm_k<8, true><<<dim3((NN + 127) / 128), 256, 0, stream>>>(
        S, Wt1s, bias1, x1bf, NN, KFUSE);

    // layer 2: aggregate x1 -> S, fused GEMM -> out (fp32)
    gatherS_k<<<(NN * 64 + 255) / 256, 256, 0, stream>>>(x1bf, sorted, base, cursor, inv, S);
    mgemm_k<4, false><<<dim3((NN + 127) / 128), 256, 0, stream>>>(
        S, Wt2s, bias2, outp, NN, KFUSE);
}

// Round 5
// 390.639 us; speedup vs baseline: 2.9508x; 1.2736x over previous
//
#include <hip/hip_runtime.h>
#include <hip/hip_bf16.h>

// Problem constants (match reference)
#define NUM_MIRNA 20000
#define NUM_GENE  30000
#define NN        50000      // total nodes
#define RR        4          // relations
#define EE        1000000    // edges
#define IN_C      128
#define HIDC      128
#define OUTC      64
#define NBASIS    10
#define NSEG      (RR * NN)  // 200000
#define KFUSE     640        // 4*128 aggregated blocks + 128 root block

typedef __attribute__((ext_vector_type(8))) short bf16x8;
typedef __attribute__((ext_vector_type(4))) float f32x4;

__device__ inline ushort f2bf(float x) {
    uint u = __float_as_uint(x);
    uint r = u + 0x7fffu + ((u >> 16) & 1u);
    return (ushort)(r >> 16);
}
__device__ inline float bf2f(ushort b) {
    return __uint_as_float((uint)b << 16);
}
__device__ inline uint pack2bf(float lo, float hi) {
    return (uint)f2bf(lo) | ((uint)f2bf(hi) << 16);
}

// ---------------------------------------------------------------------------
// transpose+cast: Wt[o][k] = bf16(W[k][o]);  W: [K][OC]  (input projections)
__global__ void tcast_k(const float* __restrict__ W, ushort* __restrict__ Wt,
                        int K, int OC) {
    int idx = blockIdx.x * 256 + threadIdx.x;
    if (idx >= K * OC) return;
    int o = idx / K, k = idx % K;
    Wt[idx] = f2bf(W[(size_t)k * OC + o]);
}

// Build stacked transposed fused weight: Wt[o][k], k in [0,640)
__global__ void buildW_k(const float* __restrict__ comp, const float* __restrict__ basis,
                         const float* __restrict__ root, ushort* __restrict__ Wt, int O) {
    int idx = blockIdx.x * 256 + threadIdx.x;
    if (idx >= O * KFUSE) return;
    int o = idx / KFUSE, k = idx % KFUSE;
    float acc;
    if (k < 512) {
        int r = k >> 7, i = k & 127;
        acc = 0.f;
#pragma unroll
        for (int b = 0; b < NBASIS; ++b)
            acc += comp[r * NBASIS + b] * basis[((size_t)b * 128 + i) * O + o];
    } else {
        acc = root[(size_t)(k - 512) * O + o];
    }
    Wt[idx] = f2bf(acc);
}

// ---------------------------------------------------------------------------
// MFMA bf16 GEMM: C[M][OC] = A[M][K] @ Wt[OC][K]^T (+bias)
// A is bf16 (A_F32=false) or fp32 converted on the fly (A_F32=true).
template <int NT, bool OUT_BF16, bool A_F32>
__global__ __launch_bounds__(256) void mgemm_k(
    const void* __restrict__ Av, const ushort* __restrict__ Wt,
    const float* __restrict__ bias, void* __restrict__ Cout, int M, int K)
{
    constexpr int MT = 2;
    constexpr int OC = NT * 16;
    const int lane = threadIdx.x & 63;
    const int wid  = threadIdx.x >> 6;
    const int l15  = lane & 15;
    const int lg   = lane >> 4;
    const int rowBase = blockIdx.x * (4 * MT * 16) + wid * (MT * 16);

    f32x4 acc[MT][NT];
#pragma unroll
    for (int mt = 0; mt < MT; ++mt)
#pragma unroll
        for (int nt = 0; nt < NT; ++nt)
            acc[mt][nt] = (f32x4){0.f, 0.f, 0.f, 0.f};

    int ar[MT];
#pragma unroll
    for (int mt = 0; mt < MT; ++mt) {
        int r = rowBase + mt * 16 + l15;
        ar[mt] = (r < M) ? r : (M - 1);
    }

    for (int kc = 0; kc < K; kc += 32) {
        int ka = kc + lg * 8;
        bf16x8 a[MT];
#pragma unroll
        for (int mt = 0; mt < MT; ++mt) {
            if (A_F32) {
                const float* Af = (const float*)Av;
                float4 f0 = *(const float4*)(Af + (size_t)ar[mt] * K + ka);
                float4 f1 = *(const float4*)(Af + (size_t)ar[mt] * K + ka + 4);
                bf16x8 t;
                t[0] = (short)f2bf(f0.x); t[1] = (short)f2bf(f0.y);
                t[2] = (short)f2bf(f0.z); t[3] = (short)f2bf(f0.w);
                t[4] = (short)f2bf(f1.x); t[5] = (short)f2bf(f1.y);
                t[6] = (short)f2bf(f1.z); t[7] = (short)f2bf(f1.w);
                a[mt] = t;
            } else {
                const ushort* Ab = (const ushort*)Av;
                a[mt] = *(const bf16x8*)(Ab + (size_t)ar[mt] * K + ka);
            }
        }
#pragma unroll
        for (int nt = 0; nt < NT; ++nt) {
            bf16x8 b = *(const bf16x8*)(Wt + (size_t)(nt * 16 + l15) * K + ka);
#pragma unroll
            for (int mt = 0; mt < MT; ++mt)
                acc[mt][nt] = __builtin_amdgcn_mfma_f32_16x16x32_bf16(
                    a[mt], b, acc[mt][nt], 0, 0, 0);
        }
    }

#pragma unroll
    for (int nt = 0; nt < NT; ++nt) {
        int n = nt * 16 + l15;
        float bv = bias ? bias[n] : 0.f;
#pragma unroll
        for (int mt = 0; mt < MT; ++mt) {
#pragma unroll
            for (int q = 0; q < 4; ++q) {
                int m = rowBase + mt * 16 + lg * 4 + q;
                if (m < M) {
                    float v = acc[mt][nt][q] + bv;
                    size_t off = (size_t)m * OC + n;
                    if (OUT_BF16) ((ushort*)Cout)[off] = f2bf(v);
                    else          ((float*)Cout)[off]  = v;
                }
            }
        }
    }
}

// ---------------------------------------------------------------------------
// CSR build: counts -> exclusive scan -> cursor fill
__global__ void count_k(const int* __restrict__ et, const int* __restrict__ dstA,
                        int* __restrict__ cnt, int E) {
    int e = blockIdx.x * 256 + threadIdx.x;
    if (e < E) atomicAdd(&cnt[et[e] * NN + dstA[e]], 1);
}

#define SCAN_B 256
#define SCAN_I 8
#define SCAN_T (SCAN_B * SCAN_I)   // 2048 elems per block

__global__ void scan1_k(const int* __restrict__ in, int* __restrict__ out,
                        int* __restrict__ bsum, int n) {
    __shared__ int sm[SCAN_B];
    int b = blockIdx.x;
    int t = threadIdx.x;
    int basei = b * SCAN_T + t * SCAN_I;
    int v[SCAN_I]; int s = 0;
#pragma unroll
    for (int i = 0; i < SCAN_I; ++i) {
        int idx = basei + i;
        v[i] = (idx < n) ? in[idx] : 0;
        s += v[i];
    }
    sm[t] = s; __syncthreads();
    for (int off = 1; off < SCAN_B; off <<= 1) {
        int x = (t >= off) ? sm[t - off] : 0;
        __syncthreads();
        sm[t] += x;
        __syncthreads();
    }
    int run = (t > 0) ? sm[t - 1] : 0;
    if (t == SCAN_B - 1) bsum[b] = sm[t];
#pragma unroll
    for (int i = 0; i < SCAN_I; ++i) {
        int idx = basei + i;
        if (idx < n) out[idx] = run;
        run += v[i];
    }
}

__global__ void scan2_k(int* __restrict__ bsum, int nb) {
    __shared__ int sm[256];
    int t = threadIdx.x;
    int v = (t < nb) ? bsum[t] : 0;
    sm[t] = v; __syncthreads();
    for (int off = 1; off < 256; off <<= 1) {
        int x = (t >= off) ? sm[t - off] : 0;
        __syncthreads();
        sm[t] += x;
        __syncthreads();
    }
    if (t < nb) bsum[t] = sm[t] - v;
}

__global__ void scan3_k(int* __restrict__ out, const int* __restrict__ bsum, int n) {
    int i = blockIdx.x * 256 + threadIdx.x;
    if (i < n) out[i] += bsum[i / SCAN_T];
}

__global__ void invcur_k(const int* __restrict__ cnt, const int* __restrict__ base,
                         float* __restrict__ inv, int* __restrict__ cursor, int n) {
    int i = blockIdx.x * 256 + threadIdx.x;
    if (i < n) {
        inv[i] = 1.0f / fmaxf((float)cnt[i], 1.0f);
        cursor[i] = base[i];
    }
}

__global__ void fill_k(const int* __restrict__ et, const int* __restrict__ srcA,
                       const int* __restrict__ dstA, int* __restrict__ cursor,
                       int* __restrict__ sorted, int E) {
    int e = blockIdx.x * 256 + threadIdx.x;
    if (e < E) {
        int seg = et[e] * NN + dstA[e];
        int pos = atomicAdd(&cursor[seg], 1);
        sorted[pos] = srcA[e];
    }
}

// ---------------------------------------------------------------------------
// Aggregate x rows per (relation, dst) into fused-K matrix S (bf16):
// S[d][r*128+c] = inv[r,d] * sum_{e in seg(r,d)} x[src_e][c];  S[d][512+c] = x[d][c]
// One wave per dst. Lanes split 4 slots x 16 colgroups; each lane loads uint4
// (16 B) so 4 rows (1 KB) are in flight per step; indices prefetched 64 at a
// time with one coalesced load; slot partials combined via shfl_xor.
__global__ __launch_bounds__(256) void gatherS_k(
    const ushort* __restrict__ x, const int* __restrict__ sorted,
    const int* __restrict__ base, const int* __restrict__ segend,
    const float* __restrict__ inv, ushort* __restrict__ S)
{
    int d = (blockIdx.x * 256 + threadIdx.x) >> 6;
    int lane = threadIdx.x & 63;
    if (d >= NN) return;
    const uint4* xp = (const uint4*)x;   // 16 uint4 per 128-col row
    uint4* Sp = (uint4*)S;               // 80 uint4 per 640-col row
    const int slot = lane >> 4;          // 0..3
    const int cg   = lane & 15;          // uint4 index within row

#pragma unroll
    for (int r = 0; r < RR; ++r) {
        int seg = r * NN + d;
        int s0 = base[seg], s1 = segend[seg];
        float wt = inv[seg];
        float acc[8];
#pragma unroll
        for (int t = 0; t < 8; ++t) acc[t] = 0.f;

        for (int i0 = s0; i0 < s1; i0 += 64) {
            int n = s1 - i0; if (n > 64) n = 64;
            int idx = 0;
            if (lane < n) idx = sorted[i0 + lane];
            for (int j = 0; j < n; j += 4) {
                int e = j + slot;
                int src = __shfl(idx, e);
                if (e < n) {
                    uint4 v = xp[(size_t)src * 16 + cg];
                    acc[0] += bf2f((ushort)(v.x & 0xffffu));
                    acc[1] += bf2f((ushort)(v.x >> 16));
                    acc[2] += bf2f((ushort)(v.y & 0xffffu));
                    acc[3] += bf2f((ushort)(v.y >> 16));
                    acc[4] += bf2f((ushort)(v.z & 0xffffu));
                    acc[5] += bf2f((ushort)(v.z >> 16));
                    acc[6] += bf2f((ushort)(v.w & 0xffffu));
                    acc[7] += bf2f((ushort)(v.w >> 16));
                }
            }
        }
#pragma unroll
        for (int t = 0; t < 8; ++t) {
            acc[t] += __shfl_xor(acc[t], 16);
            acc[t] += __shfl_xor(acc[t], 32);
            acc[t] *= wt;
        }
        if (slot == 0) {
            uint4 o;
            o.x = pack2bf(acc[0], acc[1]);
            o.y = pack2bf(acc[2], acc[3]);
            o.z = pack2bf(acc[4], acc[5]);
            o.w = pack2bf(acc[6], acc[7]);
            Sp[(size_t)d * 80 + r * 16 + cg] = o;
        }
    }
    // root block: copy own row
    ((uint*)S)[(size_t)d * 320 + 256 + lane] = ((const uint*)x)[(size_t)d * 64 + lane];
}

// ---------------------------------------------------------------------------
extern "C" void kernel_launch(void* const* d_in, const int* in_sizes, int n_in,
                              void* d_out, int out_size, void* d_ws, size_t ws_size,
                              hipStream_t stream) {
    const float* x_mirna = (const float*)d_in[0];
    const float* x_gene  = (const float*)d_in[1];
    const int*   eidx    = (const int*)d_in[2];
    const int*   etype   = (const int*)d_in[3];
    const float* lin_w_m = (const float*)d_in[4];
    const float* lin_b_m = (const float*)d_in[5];
    const float* lin_w_g = (const float*)d_in[6];
    const float* lin_b_g = (const float*)d_in[7];
    const float* comp1   = (const float*)d_in[8];
    const float* basis1  = (const float*)d_in[9];
    const float* root1   = (const float*)d_in[10];
    const float* bias1   = (const float*)d_in[11];
    const float* comp2   = (const float*)d_in[12];
    const float* basis2  = (const float*)d_in[13];
    const float* root2   = (const float*)d_in[14];
    const float* bias2   = (const float*)d_in[15];

    const int* srcA = eidx;
    const int* dstA = eidx + EE;

    // workspace layout (bytes)
    char* p = (char*)d_ws;
    ushort* x0bf = (ushort*)p; p += (size_t)NN * IN_C * 2;
    ushort* x1bf = (ushort*)p; p += (size_t)NN * HIDC * 2;
    ushort* S    = (ushort*)p; p += (size_t)NN * KFUSE * 2;     // 64 MB
    ushort* Wtm  = (ushort*)p; p += (size_t)IN_C * 256 * 2;
    ushort* Wtg  = (ushort*)p; p += (size_t)IN_C * 512 * 2;
    ushort* Wt1s = (ushort*)p; p += (size_t)HIDC * KFUSE * 2;
    ushort* Wt2s = (ushort*)p; p += (size_t)OUTC * KFUSE * 2;
    float* inv   = (float*)p;  p += (size_t)NSEG * 4;
    int* cnt     = (int*)p;    p += (size_t)NSEG * 4;
    int* base    = (int*)p;    p += (size_t)NSEG * 4;
    int* cursor  = (int*)p;    p += (size_t)NSEG * 4;
    int* bsum    = (int*)p;    p += 1024;
    int* sorted  = (int*)p;    p += (size_t)EE * 4;

    float* outp = (float*)d_out;

    hipMemsetAsync(cnt, 0, NSEG * sizeof(int), stream);

    // packed transposed weights
    tcast_k<<<(256 * IN_C + 255) / 256, 256, 0, stream>>>(lin_w_m, Wtm, 256, IN_C);
    tcast_k<<<(512 * IN_C + 255) / 256, 256, 0, stream>>>(lin_w_g, Wtg, 512, IN_C);
    buildW_k<<<(HIDC * KFUSE + 255) / 256, 256, 0, stream>>>(comp1, basis1, root1, Wt1s, HIDC);
    buildW_k<<<(OUTC * KFUSE + 255) / 256, 256, 0, stream>>>(comp2, basis2, root2, Wt2s, OUTC);

    // CSR build
    count_k<<<(EE + 255) / 256, 256, 0, stream>>>(etype, dstA, cnt, EE);
    int nb = (NSEG + SCAN_T - 1) / SCAN_T;
    scan1_k<<<nb, SCAN_B, 0, stream>>>(cnt, base, bsum, NSEG);
    scan2_k<<<1, 256, 0, stream>>>(bsum, nb);
    scan3_k<<<(NSEG + 255) / 256, 256, 0, stream>>>(base, bsum, NSEG);
    invcur_k<<<(NSEG + 255) / 256, 256, 0, stream>>>(cnt, base, inv, cursor, NSEG);
    fill_k<<<(EE + 255) / 256, 256, 0, stream>>>(etype, srcA, dstA, cursor, sorted, EE);

    // input projections (fp32 A converted in-kernel) -> x0bf
    mgemm_k<8, true, true><<<dim3((NUM_MIRNA + 127) / 128), 256, 0, stream>>>(
        x_mirna, Wtm, lin_b_m, x0bf, NUM_MIRNA, 256);
    mgemm_k<8, true, true><<<dim3((NUM_GENE + 127) / 128), 256, 0, stream>>>(
        x_gene, Wtg, lin_b_g, x0bf + (size_t)NUM_MIRNA * IN_C, NUM_GENE, 512);

    // layer 1: aggregate x0 -> S, then fused [rel GEMMs + root + bias]
    gatherS_k<<<(NN * 64 + 255) / 256, 256, 0, stream>>>(x0bf, sorted, base, cursor, inv, S);
    mgemm_k<8, true, false><<<dim3((NN + 127) / 128), 256, 0, stream>>>(
        S, Wt1s, bias1, x1bf, NN, KFUSE);

    // layer 2: aggregate x1 -> S, fused GEMM -> out (fp32)
    gatherS_k<<<(NN * 64 + 255) / 256, 256, 0, stream>>>(x1bf, sorted, base, cursor, inv, S);
    mgemm_k<4, false, false><<<dim3((NN + 127) / 128), 256, 0, stream>>>(
        S, Wt2s, bias2, outp, NN, KFUSE);
}

// Round 6
// 385.077 us; speedup vs baseline: 2.9934x; 1.0144x over previous
//
#include <hip/hip_runtime.h>
#include <hip/hip_bf16.h>

// Problem constants (match reference)
#define NUM_MIRNA 20000
#define NUM_GENE  30000
#define NN        50000      // total nodes
#define RR        4          // relations
#define EE        1000000    // edges
#define IN_C      128
#define HIDC      128
#define OUTC      64
#define NBASIS    10
#define NSEG      (RR * NN)  // 200000, seg = dst*4 + r
#define KFUSE     640        // 4*128 aggregated blocks + 128 root block
#define SROW      512        // S row length (bf16 cols) — root block read from x

#define NBKT   64            // dst-range buckets (49 used)
#define BSH    10            // bucket = dst >> 10
#define CHUNK  4096
#define NCHUNK ((EE + CHUNK - 1) / CHUNK)   // 245
#define CPB    7             // max chunks per bucket for fill2 grid

typedef __attribute__((ext_vector_type(8))) short bf16x8;
typedef __attribute__((ext_vector_type(4))) float f32x4;

__device__ inline ushort f2bf(float x) {
    uint u = __float_as_uint(x);
    uint r = u + 0x7fffu + ((u >> 16) & 1u);
    return (ushort)(r >> 16);
}
__device__ inline float bf2f(ushort b) {
    return __uint_as_float((uint)b << 16);
}
__device__ inline uint pack2bf(float lo, float hi) {
    return (uint)f2bf(lo) | ((uint)f2bf(hi) << 16);
}

// ---------------------------------------------------------------------------
// transpose+cast: Wt[o][k] = bf16(W[k][o]);  W: [K][OC]  (input projections)
__global__ void tcast_k(const float* __restrict__ W, ushort* __restrict__ Wt,
                        int K, int OC) {
    int idx = blockIdx.x * 256 + threadIdx.x;
    if (idx >= K * OC) return;
    int o = idx / K, k = idx % K;
    Wt[idx] = f2bf(W[(size_t)k * OC + o]);
}

// Build stacked transposed fused weight: Wt[o][k], k in [0,640)
__global__ void buildW_k(const float* __restrict__ comp, const float* __restrict__ basis,
                         const float* __restrict__ root, ushort* __restrict__ Wt, int O) {
    int idx = blockIdx.x * 256 + threadIdx.x;
    if (idx >= O * KFUSE) return;
    int o = idx / KFUSE, k = idx % KFUSE;
    float acc;
    if (k < 512) {
        int r = k >> 7, i = k & 127;
        acc = 0.f;
#pragma unroll
        for (int b = 0; b < NBASIS; ++b)
            acc += comp[r * NBASIS + b] * basis[((size_t)b * 128 + i) * O + o];
    } else {
        acc = root[(size_t)(k - 512) * O + o];
    }
    Wt[idx] = f2bf(acc);
}

// ---------------------------------------------------------------------------
// MFMA bf16 GEMM: C[M][OC] = A[M][K] @ Wt[OC][K]^T (+bias)
// A_F32: A is fp32, converted on the fly (row stride K).
// ROOTX: K==KFUSE; first 512 k-cols from Av (row stride SROW), last 128 from
//        xroot (row stride IN_C) — avoids materializing the root copy in S.
template <int NT, bool OUT_BF16, bool A_F32, bool ROOTX>
__global__ __launch_bounds__(256) void mgemm_k(
    const void* __restrict__ Av, const ushort* __restrict__ xroot,
    const ushort* __restrict__ Wt, const float* __restrict__ bias,
    void* __restrict__ Cout, int M, int K)
{
    constexpr int MT = 2;
    constexpr int OC = NT * 16;
    const int lane = threadIdx.x & 63;
    const int wid  = threadIdx.x >> 6;
    const int l15  = lane & 15;
    const int lg   = lane >> 4;
    const int rowBase = blockIdx.x * (4 * MT * 16) + wid * (MT * 16);
    const int AS = ROOTX ? SROW : K;

    f32x4 acc[MT][NT];
#pragma unroll
    for (int mt = 0; mt < MT; ++mt)
#pragma unroll
        for (int nt = 0; nt < NT; ++nt)
            acc[mt][nt] = (f32x4){0.f, 0.f, 0.f, 0.f};

    int ar[MT];
#pragma unroll
    for (int mt = 0; mt < MT; ++mt) {
        int r = rowBase + mt * 16 + l15;
        ar[mt] = (r < M) ? r : (M - 1);
    }

    for (int kc = 0; kc < K; kc += 32) {
        int ka = kc + lg * 8;
        bf16x8 a[MT];
#pragma unroll
        for (int mt = 0; mt < MT; ++mt) {
            if (A_F32) {
                const float* Af = (const float*)Av;
                float4 f0 = *(const float4*)(Af + (size_t)ar[mt] * K + ka);
                float4 f1 = *(const float4*)(Af + (size_t)ar[mt] * K + ka + 4);
                bf16x8 t;
                t[0] = (short)f2bf(f0.x); t[1] = (short)f2bf(f0.y);
                t[2] = (short)f2bf(f0.z); t[3] = (short)f2bf(f0.w);
                t[4] = (short)f2bf(f1.x); t[5] = (short)f2bf(f1.y);
                t[6] = (short)f2bf(f1.z); t[7] = (short)f2bf(f1.w);
                a[mt] = t;
            } else if (!ROOTX || kc < SROW) {
                const ushort* Ab = (const ushort*)Av;
                a[mt] = *(const bf16x8*)(Ab + (size_t)ar[mt] * AS + ka);
            } else {
                a[mt] = *(const bf16x8*)(xroot + (size_t)ar[mt] * IN_C + (ka - SROW));
            }
        }
#pragma unroll
        for (int nt = 0; nt < NT; ++nt) {
            bf16x8 b = *(const bf16x8*)(Wt + (size_t)(nt * 16 + l15) * K + ka);
#pragma unroll
            for (int mt = 0; mt < MT; ++mt)
                acc[mt][nt] = __builtin_amdgcn_mfma_f32_16x16x32_bf16(
                    a[mt], b, acc[mt][nt], 0, 0, 0);
        }
    }

#pragma unroll
    for (int nt = 0; nt < NT; ++nt) {
        int n = nt * 16 + l15;
        float bv = bias ? bias[n] : 0.f;
#pragma unroll
        for (int mt = 0; mt < MT; ++mt) {
#pragma unroll
            for (int q = 0; q < 4; ++q) {
                int m = rowBase + mt * 16 + lg * 4 + q;
                if (m < M) {
                    float v = acc[mt][nt][q] + bv;
                    size_t off = (size_t)m * OC + n;
                    if (OUT_BF16) ((ushort*)Cout)[off] = f2bf(v);
                    else          ((float*)Cout)[off]  = v;
                }
            }
        }
    }
}

// ---------------------------------------------------------------------------
// Bucketed CSR build.
// bs0: per-bucket edge counts (LDS histogram per chunk).
__global__ __launch_bounds__(256) void bs0_k(const int* __restrict__ dstA,
                                             int* __restrict__ bcnt) {
    __shared__ int h[NBKT];
    int t = threadIdx.x;
    if (t < NBKT) h[t] = 0;
    __syncthreads();
    int e0 = blockIdx.x * CHUNK;
    int n = EE - e0; if (n > CHUNK) n = CHUNK;
    for (int i = t; i < n; i += 256)
        atomicAdd(&h[dstA[e0 + i] >> BSH], 1);
    __syncthreads();
    if (t < NBKT && h[t]) atomicAdd(&bcnt[t], h[t]);
}

// bscan: exclusive scan of 64 bucket counts (trivial size)
__global__ void bscan_k(const int* __restrict__ bcnt, int* __restrict__ bbase,
                        int* __restrict__ bcur) {
    if (threadIdx.x == 0) {
        int run = 0;
        for (int i = 0; i < NBKT; ++i) { bbase[i] = run; bcur[i] = run; run += bcnt[i]; }
    }
}

// bs1: multi-split edges into bucket-contiguous (src, seg) payload with dense
// per-(block,bucket) runs; fused per-segment count.
__global__ __launch_bounds__(256) void bs1_k(const int* __restrict__ srcA,
                                             const int* __restrict__ dstA,
                                             const int* __restrict__ et,
                                             int* __restrict__ bcur,
                                             int* __restrict__ bsrc,
                                             int* __restrict__ bseg,
                                             int* __restrict__ cnt) {
    __shared__ int h[NBKT], cur[NBKT], boff[NBKT];
    __shared__ int lseg[CHUNK];
    __shared__ int lsrc[CHUNK];
    int t = threadIdx.x;
    if (t < NBKT) { h[t] = 0; cur[t] = 0; }
    __syncthreads();
    int e0 = blockIdx.x * CHUNK;
    int n = EE - e0; if (n > CHUNK) n = CHUNK;
    for (int i = t; i < n; i += 256) {
        int e = e0 + i;
        int d = dstA[e];
        int s2 = d * 4 + et[e];
        lseg[i] = s2;
        lsrc[i] = srcA[e];
        atomicAdd(&h[d >> BSH], 1);
    }
    __syncthreads();
    if (t < NBKT && h[t]) boff[t] = atomicAdd(&bcur[t], h[t]);
    __syncthreads();
    for (int i = t; i < n; i += 256) {
        int s2 = lseg[i];
        int b = s2 >> (BSH + 2);
        int slot = atomicAdd(&cur[b], 1);
        int pos = boff[b] + slot;
        bsrc[pos] = lsrc[i];
        bseg[pos] = s2;
        atomicAdd(&cnt[s2], 1);
    }
}

// ---------------------------------------------------------------------------
// Segment-offset scan (counts -> exclusive base)
#define SCAN_B 256
#define SCAN_I 8
#define SCAN_T (SCAN_B * SCAN_I)   // 2048 elems per block

__global__ void scan1_k(const int* __restrict__ in, int* __restrict__ out,
                        int* __restrict__ bsum, int n) {
    __shared__ int sm[SCAN_B];
    int b = blockIdx.x;
    int t = threadIdx.x;
    int basei = b * SCAN_T + t * SCAN_I;
    int v[SCAN_I]; int s = 0;
#pragma unroll
    for (int i = 0; i < SCAN_I; ++i) {
        int idx = basei + i;
        v[i] = (idx < n) ? in[idx] : 0;
        s += v[i];
    }
    sm[t] = s; __syncthreads();
    for (int off = 1; off < SCAN_B; off <<= 1) {
        int x = (t >= off) ? sm[t - off] : 0;
        __syncthreads();
        sm[t] += x;
        __syncthreads();
    }
    int run = (t > 0) ? sm[t - 1] : 0;
    if (t == SCAN_B - 1) bsum[b] = sm[t];
#pragma unroll
    for (int i = 0; i < SCAN_I; ++i) {
        int idx = basei + i;
        if (idx < n) out[idx] = run;
        run += v[i];
    }
}

__global__ void scan2_k(int* __restrict__ bsum, int nb) {
    __shared__ int sm[256];
    int t = threadIdx.x;
    int v = (t < nb) ? bsum[t] : 0;
    sm[t] = v; __syncthreads();
    for (int off = 1; off < 256; off <<= 1) {
        int x = (t >= off) ? sm[t - off] : 0;
        __syncthreads();
        sm[t] += x;
        __syncthreads();
    }
    if (t < nb) bsum[t] = sm[t] - v;
}

// scan3 + inv + cursor init, fused
__global__ void scan3inv_k(int* __restrict__ base, const int* __restrict__ bsum,
                           const int* __restrict__ cnt, float* __restrict__ inv,
                           int* __restrict__ cursor, int n) {
    int i = blockIdx.x * 256 + threadIdx.x;
    if (i < n) {
        int b = base[i] + bsum[i / SCAN_T];
        base[i] = b;
        cursor[i] = b;
        inv[i] = 1.0f / fmaxf((float)cnt[i], 1.0f);
    }
}

// fill2: per-bucket scatter into sorted[]; blockIdx = bucket + NBKT*chunk so
// all chunks of bucket b run on XCD b%8 (NBKT%8==0) -> writes stay in one L2.
__global__ __launch_bounds__(256) void fill2_k(const int* __restrict__ bsrc,
                                               const int* __restrict__ bseg,
                                               const int* __restrict__ bbase,
                                               const int* __restrict__ bcnt,
                                               int* __restrict__ cursor,
                                               int* __restrict__ sorted) {
    int b   = blockIdx.x & (NBKT - 1);
    int cwb = blockIdx.x >> 6;
    int s = bbase[b] + cwb * CHUNK;
    int e = bbase[b] + bcnt[b];
    if (e > s + CHUNK) e = s + CHUNK;
    for (int i = s + (int)threadIdx.x; i < e; i += 256) {
        int seg = bseg[i];
        int pos = atomicAdd(&cursor[seg], 1);
        sorted[pos] = bsrc[i];
    }
}

// ---------------------------------------------------------------------------
// Aggregate x rows per (relation, dst) into S (bf16, SROW=512 cols):
// S[d][r*128+c] = inv[d*4+r] * sum_{e in seg(d,r)} x[src_e][c]
// One wave per dst; 4 row-slots x 16 colgroups; uint4 per lane (1 KB/step in
// flight); 64 indices prefetched coalesced; slot partials via shfl_xor.
__global__ __launch_bounds__(256) void gatherS_k(
    const ushort* __restrict__ x, const int* __restrict__ sorted,
    const int* __restrict__ base, const int* __restrict__ segend,
    const float* __restrict__ inv, ushort* __restrict__ S)
{
    int d = (blockIdx.x * 256 + threadIdx.x) >> 6;
    int lane = threadIdx.x & 63;
    if (d >= NN) return;
    const uint4* xp = (const uint4*)x;   // 16 uint4 per 128-col row
    uint4* Sp = (uint4*)S;               // 64 uint4 per 512-col row
    const int slot = lane >> 4;          // 0..3
    const int cg   = lane & 15;          // uint4 index within row

#pragma unroll
    for (int r = 0; r < RR; ++r) {
        int seg = d * 4 + r;
        int s0 = base[seg], s1 = segend[seg];
        float wt = inv[seg];
        float acc[8];
#pragma unroll
        for (int t = 0; t < 8; ++t) acc[t] = 0.f;

        for (int i0 = s0; i0 < s1; i0 += 64) {
            int n = s1 - i0; if (n > 64) n = 64;
            int idx = 0;
            if (lane < n) idx = sorted[i0 + lane];
            for (int j = 0; j < n; j += 4) {
                int e = j + slot;
                int src = __shfl(idx, e);
                if (e < n) {
                    uint4 v = xp[(size_t)src * 16 + cg];
                    acc[0] += bf2f((ushort)(v.x & 0xffffu));
                    acc[1] += bf2f((ushort)(v.x >> 16));
                    acc[2] += bf2f((ushort)(v.y & 0xffffu));
                    acc[3] += bf2f((ushort)(v.y >> 16));
                    acc[4] += bf2f((ushort)(v.z & 0xffffu));
                    acc[5] += bf2f((ushort)(v.z >> 16));
                    acc[6] += bf2f((ushort)(v.w & 0xffffu));
                    acc[7] += bf2f((ushort)(v.w >> 16));
                }
            }
        }
#pragma unroll
        for (int t = 0; t < 8; ++t) {
            acc[t] += __shfl_xor(acc[t], 16);
            acc[t] += __shfl_xor(acc[t], 32);
            acc[t] *= wt;
        }
        if (slot == 0) {
            uint4 o;
            o.x = pack2bf(acc[0], acc[1]);
            o.y = pack2bf(acc[2], acc[3]);
            o.z = pack2bf(acc[4], acc[5]);
            o.w = pack2bf(acc[6], acc[7]);
            Sp[(size_t)d * 64 + r * 16 + cg] = o;
        }
    }
}

// ---------------------------------------------------------------------------
extern "C" void kernel_launch(void* const* d_in, const int* in_sizes, int n_in,
                              void* d_out, int out_size, void* d_ws, size_t ws_size,
                              hipStream_t stream) {
    const float* x_mirna = (const float*)d_in[0];
    const float* x_gene  = (const float*)d_in[1];
    const int*   eidx    = (const int*)d_in[2];
    const int*   etype   = (const int*)d_in[3];
    const float* lin_w_m = (const float*)d_in[4];
    const float* lin_b_m = (const float*)d_in[5];
    const float* lin_w_g = (const float*)d_in[6];
    const float* lin_b_g = (const float*)d_in[7];
    const float* comp1   = (const float*)d_in[8];
    const float* basis1  = (const float*)d_in[9];
    const float* root1   = (const float*)d_in[10];
    const float* bias1   = (const float*)d_in[11];
    const float* comp2   = (const float*)d_in[12];
    const float* basis2  = (const float*)d_in[13];
    const float* root2   = (const float*)d_in[14];
    const float* bias2   = (const float*)d_in[15];

    const int* srcA = eidx;
    const int* dstA = eidx + EE;

    // workspace layout (bytes)
    char* p = (char*)d_ws;
    ushort* x0bf = (ushort*)p; p += (size_t)NN * IN_C * 2;
    ushort* x1bf = (ushort*)p; p += (size_t)NN * HIDC * 2;
    ushort* S    = (ushort*)p; p += (size_t)NN * SROW * 2;      // 51.2 MB
    ushort* Wtm  = (ushort*)p; p += (size_t)IN_C * 256 * 2;
    ushort* Wtg  = (ushort*)p; p += (size_t)IN_C * 512 * 2;
    ushort* Wt1s = (ushort*)p; p += (size_t)HIDC * KFUSE * 2;
    ushort* Wt2s = (ushort*)p; p += (size_t)OUTC * KFUSE * 2;
    float* inv   = (float*)p;  p += (size_t)NSEG * 4;
    int* cnt     = (int*)p;    p += (size_t)NSEG * 4;
    int* bcnt    = (int*)p;    p += NBKT * 4;                   // adjacent to cnt
    int* base    = (int*)p;    p += (size_t)NSEG * 4;
    int* cursor  = (int*)p;    p += (size_t)NSEG * 4;
    int* bsum    = (int*)p;    p += 1024;
    int* bbase   = (int*)p;    p += NBKT * 4;
    int* bcur    = (int*)p;    p += NBKT * 4;
    int* sorted  = (int*)p;    p += (size_t)EE * 4;
    int* bsrc    = (int*)p;    p += (size_t)EE * 4;
    int* bseg    = (int*)p;    p += (size_t)EE * 4;

    float* outp = (float*)d_out;

    // zero cnt + bcnt in one memset (adjacent)
    hipMemsetAsync(cnt, 0, (size_t)(NSEG + NBKT) * sizeof(int), stream);

    // packed transposed weights
    tcast_k<<<(256 * IN_C + 255) / 256, 256, 0, stream>>>(lin_w_m, Wtm, 256, IN_C);
    tcast_k<<<(512 * IN_C + 255) / 256, 256, 0, stream>>>(lin_w_g, Wtg, 512, IN_C);
    buildW_k<<<(HIDC * KFUSE + 255) / 256, 256, 0, stream>>>(comp1, basis1, root1, Wt1s, HIDC);
    buildW_k<<<(OUTC * KFUSE + 255) / 256, 256, 0, stream>>>(comp2, basis2, root2, Wt2s, OUTC);

    // bucketed CSR build
    bs0_k<<<NCHUNK, 256, 0, stream>>>(dstA, bcnt);
    bscan_k<<<1, 64, 0, stream>>>(bcnt, bbase, bcur);
    bs1_k<<<NCHUNK, 256, 0, stream>>>(srcA, dstA, etype, bcur, bsrc, bseg, cnt);
    int nb = (NSEG + SCAN_T - 1) / SCAN_T;
    scan1_k<<<nb, SCAN_B, 0, stream>>>(cnt, base, bsum, NSEG);
    scan2_k<<<1, 256, 0, stream>>>(bsum, nb);
    scan3inv_k<<<(NSEG + 255) / 256, 256, 0, stream>>>(base, bsum, cnt, inv, cursor, NSEG);
    fill2_k<<<NBKT * CPB, 256, 0, stream>>>(bsrc, bseg, bbase, bcnt, cursor, sorted);

    // input projections (fp32 A converted in-kernel) -> x0bf
    mgemm_k<8, true, true, false><<<dim3((NUM_MIRNA + 127) / 128), 256, 0, stream>>>(
        x_mirna, nullptr, Wtm, lin_b_m, x0bf, NUM_MIRNA, 256);
    mgemm_k<8, true, true, false><<<dim3((NUM_GENE + 127) / 128), 256, 0, stream>>>(
        x_gene, nullptr, Wtg, lin_b_g, x0bf + (size_t)NUM_MIRNA * IN_C, NUM_GENE, 512);

    // layer 1: aggregate x0 -> S, then fused [rel GEMMs + root + bias]
    gatherS_k<<<(NN * 64 + 255) / 256, 256, 0, stream>>>(x0bf, sorted, base, cursor, inv, S);
    mgemm_k<8, true, false, true><<<dim3((NN + 127) / 128), 256, 0, stream>>>(
        S, x0bf, Wt1s, bias1, x1bf, NN, KFUSE);

    // layer 2: aggregate x1 -> S, fused GEMM -> out (fp32)
    gatherS_k<<<(NN * 64 + 255) / 256, 256, 0, stream>>>(x1bf, sorted, base, cursor, inv, S);
    mgemm_k<4, false, false, true><<<dim3((NN + 127) / 128), 256, 0, stream>>>(
        S, x1bf, Wt2s, bias2, outp, NN, KFUSE);
}